// Round 6
// baseline (282.225 us; speedup 1.0000x reference)
//
#include <hip/hip_runtime.h>
#include <math.h>

// Problem constants (E zonotope rows, content = C*H*W)
#define EROWS 64
#define NCOL  8192                   // 8*32*32
#define TAIL_OFF (EROWS * NCOL)      // floats before tail
#define TAIL_F4  (NCOL * NCOL / 4)   // 16,777,216 float4 in tail

#define STAT_BLOCKS 256              // 32 columns per stats block
#define FILL_F4_PER_BLOCK 4096       // 256 thr x 16 f4 = 64 KiB = 2 tail rows
#define FILL_BLOCKS (TAIL_F4 / FILL_F4_PER_BLOCK)   // 4096

// Native vector types
typedef float vf4 __attribute__((ext_vector_type(4)));
typedef int   vi4 __attribute__((ext_vector_type(4)));

// ws layout (bytes): val@0, flag@32768, colof@65536, tailval@98304, count@131072
#define WS_VAL(ws)     ((float*)(ws))
#define WS_FLAG(ws)    ((int*)((char*)(ws) + 32768))
#define WS_COLOF(ws)   ((int*)((char*)(ws) + 65536))
#define WS_TAILVAL(ws) ((float*)((char*)(ws) + 98304))
#define WS_COUNT(ws)   ((int*)((char*)(ws) + 131072))

// Kernel 1: per-column stats + head + body (verified R5 stats branch).
// 32 columns per block; threads (c = tid&31, eg = tid>>5) split the 63-row
// |x| reduction 8 ways via LDS; x values stay in registers for the body write.
__global__ void colstats_kernel(const float* __restrict__ x,
                                float* __restrict__ out,
                                float* __restrict__ val,
                                int* __restrict__ flag) {
    const int tid = threadIdx.x;

    __shared__ float part[256];   // partial |x| sums, [eg][c]
    __shared__ float sc[32];      // per-column scale

    const int c   = tid & 31;
    const int eg  = tid >> 5;                 // 0..7
    const int col = blockIdx.x * 32 + c;

    float xv[8];
    int   ev[8];
    int   n = 0;
    float s = 0.f;
    #pragma unroll
    for (int j = 0; j < 8; ++j) {
        int e = eg + 8 * j;
        if (e == 0) continue;                 // row 0 is the center
        float v = x[e * NCOL + col];
        xv[n] = v; ev[n] = e; ++n;
        s += fabsf(v);
    }
    part[eg * 32 + c] = s;
    __syncthreads();

    if (tid < 32) {
        float err = 0.f;
        #pragma unroll
        for (int g = 0; g < 8; ++g)
            err += part[g * 32 + tid];

        int   k  = blockIdx.x * 32 + tid;
        float x0 = x[k];
        float upper = x0 + err;
        float lower = x0 - err;

        float cross  = (lower * upper < 0.f) ? 1.f : 0.f;
        float nonneg = (lower >= 0.f) ? 1.f : 0.f;

        float lam = nonneg + cross * upper / (upper - lower);
        if (isnan(lam)) lam = 0.5f;

        float delta = fmaxf(-lam * lower, (1.f - lam) * upper);

        out[k]   = (delta * 0.5f + lam * x0) * cross + x0 * nonneg;  // head
        val[k]   = delta * 0.5f;
        flag[k]  = (cross > 0.f) ? 1 : 0;
        sc[tid]  = lam * cross + nonneg;
    }
    __syncthreads();

    float scl = sc[c];
    #pragma unroll
    for (int i = 0; i < 8; ++i) {
        if (i < n)
            out[ev[i] * NCOL + col] = xv[i] * scl;                   // body
    }
}

// Kernel 2: 256-thread stream-compaction scan (verified). Emits inverse map:
// colof[r] = column of r-th crossing, tailval[r] = val there, count = total.
__global__ void scan_kernel(const float* __restrict__ val,
                            const int* __restrict__ flag,
                            int* __restrict__ colof,
                            float* __restrict__ tailval,
                            int* __restrict__ count) {
    const int t    = threadIdx.x;        // 256 threads
    const int lane = t & 63;
    const int wave = t >> 6;             // 4 waves
    const int PER  = NCOL / 256;         // 32 consecutive columns per thread

    int f[PER];
    int mysum = 0;
    const vi4* fp = (const vi4*)(flag + t * PER);
    for (int j = 0; j < PER / 4; ++j) {
        vi4 v = fp[j];
        f[4*j+0] = v.x; f[4*j+1] = v.y; f[4*j+2] = v.z; f[4*j+3] = v.w;
        mysum += v.x + v.y + v.z + v.w;
    }

    int s = mysum;
    for (int off = 1; off < 64; off <<= 1) {
        int v = __shfl_up(s, off);
        if (lane >= off) s += v;
    }

    __shared__ int wsum[4];
    if (lane == 63) wsum[wave] = s;
    __syncthreads();
    int wbase = 0;
    for (int w = 0; w < wave; ++w) wbase += wsum[w];

    int running = wbase + s - mysum;     // exclusive prefix for this thread

    for (int j = 0; j < PER; ++j) {
        int k = t * PER + j;
        if (f[j]) {
            colof[running]   = k;
            tailval[running] = val[k];
            ++running;
        }
    }
    if (t == 255) *count = wsum[0] + wsum[1] + wsum[2] + wsum[3];
}

// Kernel 3: tail writer with inline diagonal. Each block owns 2 tail rows
// (64 KiB); every byte of the tail is written exactly once: zeros except the
// component where colof[row] falls. Scan ran in the previous launch, so
// plain loads of colof/tailval are safe (stream ordering).
__global__ void filltail_kernel(const int* __restrict__ colof,
                                const float* __restrict__ tailval,
                                const int* __restrict__ count,
                                float* __restrict__ out) {
    const int tid = threadIdx.x;
    const int b   = blockIdx.x;
    const int cnt = *count;

    const int r0 = 2 * b, r1 = 2 * b + 1;
    int   c0 = (r0 < cnt) ? colof[r0]   : -1;    // ws poisoned: guard
    float v0 = (r0 < cnt) ? tailval[r0] : 0.f;
    int   c1 = (r1 < cnt) ? colof[r1]   : -1;
    float v1 = (r1 < cnt) ? tailval[r1] : 0.f;

    vf4* base = (vf4*)out + (TAIL_OFF / 4) + (size_t)b * FILL_F4_PER_BLOCK;
    #pragma unroll
    for (int i = 0; i < 16; ++i) {
        int j   = i * 256 + tid;                 // f4 index within block
        int col = (i < 8) ? c0 : c1;             // rows: i<8 -> r0, else r1
        float tv = (i < 8) ? v0 : v1;
        int cs  = (j & 2047) << 2;               // first column of this f4
        vf4 v;
        v.x = (col == cs + 0) ? tv : 0.f;
        v.y = (col == cs + 1) ? tv : 0.f;
        v.z = (col == cs + 2) ? tv : 0.f;
        v.w = (col == cs + 3) ? tv : 0.f;
        base[j] = v;
    }
}

extern "C" void kernel_launch(void* const* d_in, const int* in_sizes, int n_in,
                              void* d_out, int out_size, void* d_ws, size_t ws_size,
                              hipStream_t stream) {
    const float* x = (const float*)d_in[0];
    float* out = (float*)d_out;

    colstats_kernel<<<STAT_BLOCKS, 256, 0, stream>>>(x, out, WS_VAL(d_ws), WS_FLAG(d_ws));
    scan_kernel<<<1, 256, 0, stream>>>(WS_VAL(d_ws), WS_FLAG(d_ws),
                                       WS_COLOF(d_ws), WS_TAILVAL(d_ws), WS_COUNT(d_ws));
    filltail_kernel<<<FILL_BLOCKS, 256, 0, stream>>>(WS_COLOF(d_ws), WS_TAILVAL(d_ws),
                                                     WS_COUNT(d_ws), out);
}